// Round 22
// baseline (73.156 us; speedup 1.0000x reference)
//
#include <hip/hip_runtime.h>
#include <math.h>

#define NB 2048
#define LL 200
#define PADL 256
#define DD 64
#define CC 9
#define HH 16
#define NW 4
#define UPB 2   // users per block (512 threads)

// r18 base (65.4us) + block-flattened phases B and C (load-balance across the
// 2 users: history lengths are uniform[50,200], so per-user partitioning makes
// each block run at max(len0,len1); flattening runs at the mean).
__global__ __launch_bounds__(512) void din_fused(
    const int* __restrict__ user_inputs,
    const int* __restrict__ record_inputs,
    const int* __restrict__ item_inputs,
    const int* __restrict__ item_cat,
    const float* __restrict__ user_emb,
    const float* __restrict__ item_emb,
    const float* __restrict__ W1,
    const float* __restrict__ b1,
    const float* __restrict__ W2,
    const float* __restrict__ b2,
    const float* __restrict__ Wt1,
    const float* __restrict__ bt1,
    const float* __restrict__ Wt2,
    const float* __restrict__ bt2,
    float* __restrict__ out)
{
  const int t  = threadIdx.x;           // 0..511
  const int uu = t >> 8;                // local user 0/1 (phase A/D)
  const int tu = t & 255;               // per-user thread index
  const int b  = blockIdx.x * UPB + uu;
  const int wave = tu >> 6;             // per-user wave 0..3 (phase A)
  const int bw   = t >> 6;              // block wave 0..7 (phase C)
  const int lane = t & 63;

  __shared__ float4 w_lds[HH * 16 * CC];     // 36.9 KB, shared by both users
  __shared__ float  w2_s[CC * HH];
  __shared__ float  b2_s[CC];
  __shared__ float  u_s[UPB][DD];
  __shared__ float  pre_s[UPB][CC][HH];
  __shared__ int    wcnt[UPB][NW][CC];
  __shared__ int    cstart[UPB][CC + 1];
  __shared__ int    ccnt[UPB][CC];
  __shared__ int    srow_sh[UPB][PADL];
  __shared__ __align__(16) float z_s[UPB][PADL];
  __shared__ float  gvec_s[UPB][CC][DD];
  __shared__ float  h2_s[UPB][CC][HH];
  __shared__ float  w2t_s[UPB][CC];

  // ---- Phase A: stage W (swizzled) + inputs + ballot ----
  #pragma unroll
  for (int k = t; k < HH * 16 * CC; k += 512) {
    int c = k >> 8;
    int ji = k & 255;                        // j*16 + i
    int j = ji >> 4, i = ji & 15;
    int phys = (ji * CC + c) ^ ((ji >> 6) << 1);
    w_lds[phys] = ((const float4*)W1)[(size_t)(c * HH + j) * 32 + 16 + i];
  }
  if (t < CC * HH) w2_s[t] = W2[t];
  if (t < CC) b2_s[t] = b2[t];

  int r = -1, c0 = -1;
  if (tu < LL) {
    r = record_inputs[b * LL + tu];
    if (r >= 0) c0 = item_cat[r];
  }
  if (tu < DD) u_s[uu][tu] = user_emb[(size_t)user_inputs[b] * DD + tu];
  srow_sh[uu][tu] = 0;                       // pad slots -> row 0

  int myrank = 0;
  #pragma unroll
  for (int c = 0; c < CC; ++c) {
    unsigned long long m = __ballot(c0 == c);  // wave is user-pure
    if (lane == 0) wcnt[uu][wave][c] = __popcll(m);
    if (c0 == c) myrank = __popcll(m & ((1ULL << lane) - 1ULL));
  }
  __syncthreads();

  if (tu == 0) {                             // one thread per user
    int acc = 0;
    #pragma unroll
    for (int c = 0; c < CC; ++c) {
      cstart[uu][c] = acc;
      int cn = wcnt[uu][0][c] + wcnt[uu][1][c] + wcnt[uu][2][c] + wcnt[uu][3][c];
      ccnt[uu][c] = cn;
      acc = (acc + cn + 3) & ~3;             // 4-aligned groups
    }
    cstart[uu][CC] = acc;
  }
  if (tu < CC * HH) {                        // pre = b1 + W1u . u
    int c = tu / HH, j = tu % HH;
    const float* wp = &W1[(size_t)(c * HH + j) * (2 * DD)];
    float acc = b1[c * HH + j];
    #pragma unroll 8
    for (int d = 0; d < DD; ++d) acc += wp[d] * u_s[uu][d];
    pre_s[uu][c][j] = acc;
  }
  __syncthreads();

  if (c0 >= 0) {                             // stable scatter
    int off = cstart[uu][c0];
    for (int w = 0; w < wave; ++w) off += wcnt[uu][w][c0];
    srow_sh[uu][off + myrank] = r;
  }
  __syncthreads();

  // ---- Phase B: score over the COMBINED slot list (block-balanced) ----
  // group g covers combined slots [g*4, g*4+4): user0 slots [0,B0), user1
  // slots [B0, B0+T1). B0 is 4-aligned by construction.
  const int B0 = cstart[0][CC];
  const int T1 = cstart[1][CC];
  {
    const int g4 = (t >> 2) * 4;             // combined slot base
    const int jq = t & 3;
    const int uu2 = (g4 >= B0) ? 1 : 0;
    const int q4  = g4 - uu2 * B0;
    if (uu2 == 0 || q4 < T1) {               // active group
      int c = 0;
      #pragma unroll
      for (int q = 0; q < CC - 1; ++q) c += (q4 >= cstart[uu2][q + 1]) ? 1 : 0;

      const int r0 = srow_sh[uu2][q4 + 0], r1 = srow_sh[uu2][q4 + 1];
      const int r2 = srow_sh[uu2][q4 + 2], r3 = srow_sh[uu2][q4 + 3];
      const float4* e0 = (const float4*)&item_emb[(size_t)r0 * DD];
      const float4* e1 = (const float4*)&item_emb[(size_t)r1 * DD];
      const float4* e2 = (const float4*)&item_emb[(size_t)r2 * DD];
      const float4* e3 = (const float4*)&item_emb[(size_t)r3 * DD];

      float acc0[4], acc1[4], acc2[4], acc3[4];
      #pragma unroll
      for (int jj = 0; jj < 4; ++jj) {
        float pv = pre_s[uu2][c][jq * 4 + jj];
        acc0[jj] = pv; acc1[jj] = pv; acc2[jj] = pv; acc3[jj] = pv;
      }

      #pragma unroll
      for (int i = 0; i < 16; ++i) {
        float4 a0 = e0[i], a1 = e1[i], a2 = e2[i], a3 = e3[i];
        #pragma unroll
        for (int jj = 0; jj < 4; ++jj) {
          int ji = (jq * 4 + jj) * 16 + i;
          float4 wv = w_lds[(ji * CC + c) ^ (jq << 1)];
          acc0[jj] += wv.x * a0.x + wv.y * a0.y + wv.z * a0.z + wv.w * a0.w;
          acc1[jj] += wv.x * a1.x + wv.y * a1.y + wv.z * a1.z + wv.w * a1.w;
          acc2[jj] += wv.x * a2.x + wv.y * a2.y + wv.z * a2.z + wv.w * a2.w;
          acc3[jj] += wv.x * a3.x + wv.y * a3.y + wv.z * a3.z + wv.w * a3.w;
        }
      }

      float s0 = 0.f, s1 = 0.f, s2 = 0.f, s3 = 0.f;
      #pragma unroll
      for (int jj = 0; jj < 4; ++jj) {
        float w2v = w2_s[c * HH + jq * 4 + jj];
        s0 += w2v * fmaxf(acc0[jj], 0.f);
        s1 += w2v * fmaxf(acc1[jj], 0.f);
        s2 += w2v * fmaxf(acc2[jj], 0.f);
        s3 += w2v * fmaxf(acc3[jj], 0.f);
      }
      // combine j-quarters (4 lanes of the group; all active together)
      s0 += __shfl_xor(s0, 1, 64); s0 += __shfl_xor(s0, 2, 64);
      s1 += __shfl_xor(s1, 1, 64); s1 += __shfl_xor(s1, 2, 64);
      s2 += __shfl_xor(s2, 1, 64); s2 += __shfl_xor(s2, 2, 64);
      s3 += __shfl_xor(s3, 1, 64); s3 += __shfl_xor(s3, 2, 64);

      if (jq == 0) {
        const float b2c = b2_s[c];
        *(float4*)&z_s[uu2][q4] = make_float4(expf(s0 + b2c), expf(s1 + b2c),
                                              expf(s2 + b2c), expf(s3 + b2c));
      }
    }
  }
  __syncthreads();

  // ---- Phase C: gvec over 18 (user,cat) pairs round-robin on 8 waves ----
  {
    const int g = lane >> 4, h = lane & 15;
    for (int p = bw; p < UPB * CC; p += 8) {
      const int uu2 = p / CC;
      const int c   = p - uu2 * CC;
      const int i0 = cstart[uu2][c], n = ccnt[uu2][c];
      float4 acc = make_float4(0.f, 0.f, 0.f, 0.f);
      float  zs  = 0.f;
      const int kmax = (n + 3) >> 2;
      #pragma unroll 4
      for (int k = 0; k < kmax; ++k) {
        const int io = 4 * k + g;
        const int rr = srow_sh[uu2][i0 + io];          // broadcast (4 addrs)
        const float zz = (io < n) ? z_s[uu2][i0 + io] : 0.f;
        const float4 ev = *(const float4*)&item_emb[(size_t)rr * DD + 4 * h];
        acc.x += zz * ev.x; acc.y += zz * ev.y;
        acc.z += zz * ev.z; acc.w += zz * ev.w;
        zs += zz;                                      // uniform within h-group
      }
      acc.x += __shfl_xor(acc.x, 16, 64); acc.y += __shfl_xor(acc.y, 16, 64);
      acc.z += __shfl_xor(acc.z, 16, 64); acc.w += __shfl_xor(acc.w, 16, 64);
      acc.x += __shfl_xor(acc.x, 32, 64); acc.y += __shfl_xor(acc.y, 32, 64);
      acc.z += __shfl_xor(acc.z, 32, 64); acc.w += __shfl_xor(acc.w, 32, 64);
      zs += __shfl_xor(zs, 16, 64);
      zs += __shfl_xor(zs, 32, 64);

      if (g == 0) {
        const float inv = 1.f / fmaxf(zs, 1e-30f);
        gvec_s[uu2][c][4 * h + 0] = acc.x * inv;
        gvec_s[uu2][c][4 * h + 1] = acc.y * inv;
        gvec_s[uu2][c][4 * h + 2] = acc.z * inv;
        gvec_s[uu2][c][4 * h + 3] = acc.w * inv;       // empty cat -> 0
      }
    }
  }
  __syncthreads();

  // ---- Phase D: top-level attention + output (per-user) ----
  if (tu < CC * HH) {
    int cc = tu / HH, j = tu % HH;
    const float* wp = &Wt1[(size_t)j * (2 * DD)];
    float a = bt1[j];
    #pragma unroll 8
    for (int d = 0; d < DD; ++d) a += wp[d] * u_s[uu][d];
    #pragma unroll 8
    for (int d = 0; d < DD; ++d) a += wp[DD + d] * gvec_s[uu][cc][d];
    h2_s[uu][cc][j] = fmaxf(a, 0.f);
  }
  __syncthreads();

  if (tu == 0) {
    float s2[CC];
    float m = -INFINITY;
    #pragma unroll
    for (int cc = 0; cc < CC; ++cc) {
      float a = bt2[0];
      #pragma unroll
      for (int j = 0; j < HH; ++j) a += Wt2[j] * h2_s[uu][cc][j];
      s2[cc] = a;
      if (ccnt[uu][cc] > 0) m = fmaxf(m, a);
    }
    if (m == -INFINITY) m = 0.f;
    float sum = 0.f;
    float z2[CC];
    #pragma unroll
    for (int cc = 0; cc < CC; ++cc) {
      z2[cc] = (ccnt[uu][cc] > 0) ? expf(s2[cc] - m) : 0.f;
      sum += z2[cc];
    }
    float inv = 1.f / fmaxf(sum, 1e-30f);
    #pragma unroll
    for (int cc = 0; cc < CC; ++cc) w2t_s[uu][cc] = z2[cc] * inv;
  }
  __syncthreads();

  if (tu < DD) {                              // one full wave per user
    float hy = 0.f;
    #pragma unroll
    for (int cc = 0; cc < CC; ++cc) hy += w2t_s[uu][cc] * gvec_s[uu][cc][tu];
    float ti = item_emb[(size_t)item_inputs[b] * DD + tu];
    float prod = hy * ti;
    #pragma unroll
    for (int off = 32; off > 0; off >>= 1)
      prod += __shfl_down(prod, off, 64);
    if (tu == 0) out[b] = prod;
  }
}

extern "C" void kernel_launch(void* const* d_in, const int* in_sizes, int n_in,
                              void* d_out, int out_size, void* d_ws, size_t ws_size,
                              hipStream_t stream) {
  const int*   user_inputs   = (const int*)d_in[0];
  const int*   record_inputs = (const int*)d_in[1];
  const int*   item_inputs   = (const int*)d_in[2];
  const int*   item_cat      = (const int*)d_in[3];
  const float* user_emb      = (const float*)d_in[4];
  const float* item_emb      = (const float*)d_in[5];
  const float* W1            = (const float*)d_in[6];
  const float* b1            = (const float*)d_in[7];
  const float* W2            = (const float*)d_in[8];
  const float* b2            = (const float*)d_in[9];
  const float* Wt1           = (const float*)d_in[10];
  const float* bt1           = (const float*)d_in[11];
  const float* Wt2           = (const float*)d_in[12];
  const float* bt2           = (const float*)d_in[13];
  float* out = (float*)d_out;

  din_fused<<<NB / UPB, 512, 0, stream>>>(user_inputs, record_inputs, item_inputs,
                                          item_cat, user_emb, item_emb,
                                          W1, b1, W2, b2, Wt1, bt1, Wt2, bt2, out);
}

// Round 23
// 65.531 us; speedup vs baseline: 1.1164x; 1.1164x over previous
//
#include <hip/hip_runtime.h>
#include <math.h>

#define NB 2048
#define LL 200
#define PADL 256
#define DD 64
#define CC 9
#define HH 16
#define NW 4
#define UPB 2   // users per block (512 threads) — best known config (r18: 65.4us)

__global__ __launch_bounds__(512) void din_fused(
    const int* __restrict__ user_inputs,
    const int* __restrict__ record_inputs,
    const int* __restrict__ item_inputs,
    const int* __restrict__ item_cat,
    const float* __restrict__ user_emb,
    const float* __restrict__ item_emb,
    const float* __restrict__ W1,
    const float* __restrict__ b1,
    const float* __restrict__ W2,
    const float* __restrict__ b2,
    const float* __restrict__ Wt1,
    const float* __restrict__ bt1,
    const float* __restrict__ Wt2,
    const float* __restrict__ bt2,
    float* __restrict__ out)
{
  const int t  = threadIdx.x;           // 0..511
  const int uu = t >> 8;                // local user 0/1
  const int tu = t & 255;               // per-user thread index
  const int b  = blockIdx.x * UPB + uu;
  const int wave = tu >> 6, lane = t & 63;

  __shared__ float4 w_lds[HH * 16 * CC];     // 36.9 KB, shared by both users
  __shared__ float  w2_s[CC * HH];
  __shared__ float  b2_s[CC];
  __shared__ float  u_s[UPB][DD];
  __shared__ float  pre_s[UPB][CC][HH];
  __shared__ int    wcnt[UPB][NW][CC];
  __shared__ int    cstart[UPB][CC + 1];
  __shared__ int    ccnt[UPB][CC];
  __shared__ int    srow_sh[UPB][PADL];
  __shared__ __align__(16) float z_s[UPB][PADL];
  __shared__ float  gvec_s[UPB][CC][DD];
  __shared__ float  h2_s[UPB][CC][HH];
  __shared__ float  w2t_s[UPB][CC];

  // ---- Phase A: stage W (swizzled) + inputs + ballot ----
  #pragma unroll
  for (int k = t; k < HH * 16 * CC; k += 512) {
    int c = k >> 8;
    int ji = k & 255;                        // j*16 + i
    int j = ji >> 4, i = ji & 15;
    int phys = (ji * CC + c) ^ ((ji >> 6) << 1);
    w_lds[phys] = ((const float4*)W1)[(size_t)(c * HH + j) * 32 + 16 + i];
  }
  if (t < CC * HH) w2_s[t] = W2[t];
  if (t < CC) b2_s[t] = b2[t];

  int r = -1, c0 = -1;
  if (tu < LL) {
    r = record_inputs[b * LL + tu];
    if (r >= 0) c0 = item_cat[r];
  }
  if (tu < DD) u_s[uu][tu] = user_emb[(size_t)user_inputs[b] * DD + tu];
  srow_sh[uu][tu] = 0;                       // pad slots -> row 0

  int myrank = 0;
  #pragma unroll
  for (int c = 0; c < CC; ++c) {
    unsigned long long m = __ballot(c0 == c);  // wave is user-pure
    if (lane == 0) wcnt[uu][wave][c] = __popcll(m);
    if (c0 == c) myrank = __popcll(m & ((1ULL << lane) - 1ULL));
  }
  __syncthreads();

  if (tu == 0) {                             // one thread per user
    int acc = 0;
    #pragma unroll
    for (int c = 0; c < CC; ++c) {
      cstart[uu][c] = acc;
      int cn = wcnt[uu][0][c] + wcnt[uu][1][c] + wcnt[uu][2][c] + wcnt[uu][3][c];
      ccnt[uu][c] = cn;
      acc = (acc + cn + 3) & ~3;             // 4-aligned groups
    }
    cstart[uu][CC] = acc;
  }
  if (tu < CC * HH) {                        // pre = b1 + W1u . u
    int c = tu / HH, j = tu % HH;
    const float* wp = &W1[(size_t)(c * HH + j) * (2 * DD)];
    float acc = b1[c * HH + j];
    #pragma unroll 8
    for (int d = 0; d < DD; ++d) acc += wp[d] * u_s[uu][d];
    pre_s[uu][c][j] = acc;
  }
  __syncthreads();

  if (c0 >= 0) {                             // stable scatter
    int off = cstart[uu][c0];
    for (int w = 0; w < wave; ++w) off += wcnt[uu][w][c0];
    srow_sh[uu][off + myrank] = r;
  }
  __syncthreads();

  // ---- Phase B: score; per-user thread = (grp, jq): 4 items x 4 hidden ----
  const int ntot = cstart[uu][CC];           // padded total (<= 228)
  {
    const int grp = tu >> 2, jq = tu & 3;
    const int q4 = grp * 4;
    if (q4 < ntot) {
      int c = 0;
      #pragma unroll
      for (int q = 0; q < CC - 1; ++q) c += (q4 >= cstart[uu][q + 1]) ? 1 : 0;

      const int r0 = srow_sh[uu][q4 + 0], r1 = srow_sh[uu][q4 + 1];
      const int r2 = srow_sh[uu][q4 + 2], r3 = srow_sh[uu][q4 + 3];
      const float4* e0 = (const float4*)&item_emb[(size_t)r0 * DD];
      const float4* e1 = (const float4*)&item_emb[(size_t)r1 * DD];
      const float4* e2 = (const float4*)&item_emb[(size_t)r2 * DD];
      const float4* e3 = (const float4*)&item_emb[(size_t)r3 * DD];

      float acc0[4], acc1[4], acc2[4], acc3[4];
      #pragma unroll
      for (int jj = 0; jj < 4; ++jj) {
        float pv = pre_s[uu][c][jq * 4 + jj];
        acc0[jj] = pv; acc1[jj] = pv; acc2[jj] = pv; acc3[jj] = pv;
      }

      #pragma unroll
      for (int i = 0; i < 16; ++i) {
        float4 a0 = e0[i], a1 = e1[i], a2 = e2[i], a3 = e3[i];
        #pragma unroll
        for (int jj = 0; jj < 4; ++jj) {
          int ji = (jq * 4 + jj) * 16 + i;
          float4 wv = w_lds[(ji * CC + c) ^ (jq << 1)];
          acc0[jj] += wv.x * a0.x + wv.y * a0.y + wv.z * a0.z + wv.w * a0.w;
          acc1[jj] += wv.x * a1.x + wv.y * a1.y + wv.z * a1.z + wv.w * a1.w;
          acc2[jj] += wv.x * a2.x + wv.y * a2.y + wv.z * a2.z + wv.w * a2.w;
          acc3[jj] += wv.x * a3.x + wv.y * a3.y + wv.z * a3.z + wv.w * a3.w;
        }
      }

      float s0 = 0.f, s1 = 0.f, s2 = 0.f, s3 = 0.f;
      #pragma unroll
      for (int jj = 0; jj < 4; ++jj) {
        float w2v = w2_s[c * HH + jq * 4 + jj];
        s0 += w2v * fmaxf(acc0[jj], 0.f);
        s1 += w2v * fmaxf(acc1[jj], 0.f);
        s2 += w2v * fmaxf(acc2[jj], 0.f);
        s3 += w2v * fmaxf(acc3[jj], 0.f);
      }
      s0 += __shfl_xor(s0, 1, 64); s0 += __shfl_xor(s0, 2, 64);
      s1 += __shfl_xor(s1, 1, 64); s1 += __shfl_xor(s1, 2, 64);
      s2 += __shfl_xor(s2, 1, 64); s2 += __shfl_xor(s2, 2, 64);
      s3 += __shfl_xor(s3, 1, 64); s3 += __shfl_xor(s3, 2, 64);

      if (jq == 0) {
        const float b2c = b2_s[c];
        *(float4*)&z_s[uu][q4] = make_float4(expf(s0 + b2c), expf(s1 + b2c),
                                             expf(s2 + b2c), expf(s3 + b2c));
      }
    }
  }
  __syncthreads();

  // ---- Phase C: gvec. per-user wave = category loop; lane (g,h) ----
  {
    const int g = lane >> 4, h = lane & 15;
    for (int c = wave; c < CC; c += NW) {
      const int i0 = cstart[uu][c], n = ccnt[uu][c];
      float4 acc = make_float4(0.f, 0.f, 0.f, 0.f);
      float  zs  = 0.f;
      const int kmax = (n + 3) >> 2;
      #pragma unroll 4
      for (int k = 0; k < kmax; ++k) {
        const int io = 4 * k + g;
        const int rr = srow_sh[uu][i0 + io];           // broadcast (4 addrs)
        const float zz = (io < n) ? z_s[uu][i0 + io] : 0.f;
        const float4 ev = *(const float4*)&item_emb[(size_t)rr * DD + 4 * h];
        acc.x += zz * ev.x; acc.y += zz * ev.y;
        acc.z += zz * ev.z; acc.w += zz * ev.w;
        zs += zz;                                      // uniform within h-group
      }
      acc.x += __shfl_xor(acc.x, 16, 64); acc.y += __shfl_xor(acc.y, 16, 64);
      acc.z += __shfl_xor(acc.z, 16, 64); acc.w += __shfl_xor(acc.w, 16, 64);
      acc.x += __shfl_xor(acc.x, 32, 64); acc.y += __shfl_xor(acc.y, 32, 64);
      acc.z += __shfl_xor(acc.z, 32, 64); acc.w += __shfl_xor(acc.w, 32, 64);
      zs += __shfl_xor(zs, 16, 64);
      zs += __shfl_xor(zs, 32, 64);

      if (g == 0) {
        const float inv = 1.f / fmaxf(zs, 1e-30f);
        gvec_s[uu][c][4 * h + 0] = acc.x * inv;
        gvec_s[uu][c][4 * h + 1] = acc.y * inv;
        gvec_s[uu][c][4 * h + 2] = acc.z * inv;
        gvec_s[uu][c][4 * h + 3] = acc.w * inv;        // empty cat -> 0
      }
    }
  }
  __syncthreads();

  // ---- Phase D: top-level attention + output ----
  if (tu < CC * HH) {
    int cc = tu / HH, j = tu % HH;
    const float* wp = &Wt1[(size_t)j * (2 * DD)];
    float a = bt1[j];
    #pragma unroll 8
    for (int d = 0; d < DD; ++d) a += wp[d] * u_s[uu][d];
    #pragma unroll 8
    for (int d = 0; d < DD; ++d) a += wp[DD + d] * gvec_s[uu][cc][d];
    h2_s[uu][cc][j] = fmaxf(a, 0.f);
  }
  __syncthreads();

  if (tu == 0) {
    float s2[CC];
    float m = -INFINITY;
    #pragma unroll
    for (int cc = 0; cc < CC; ++cc) {
      float a = bt2[0];
      #pragma unroll
      for (int j = 0; j < HH; ++j) a += Wt2[j] * h2_s[uu][cc][j];
      s2[cc] = a;
      if (ccnt[uu][cc] > 0) m = fmaxf(m, a);
    }
    if (m == -INFINITY) m = 0.f;
    float sum = 0.f;
    float z2[CC];
    #pragma unroll
    for (int cc = 0; cc < CC; ++cc) {
      z2[cc] = (ccnt[uu][cc] > 0) ? expf(s2[cc] - m) : 0.f;
      sum += z2[cc];
    }
    float inv = 1.f / fmaxf(sum, 1e-30f);
    #pragma unroll
    for (int cc = 0; cc < CC; ++cc) w2t_s[uu][cc] = z2[cc] * inv;
  }
  __syncthreads();

  if (tu < DD) {                              // one full wave per user
    float hy = 0.f;
    #pragma unroll
    for (int cc = 0; cc < CC; ++cc) hy += w2t_s[uu][cc] * gvec_s[uu][cc][tu];
    float ti = item_emb[(size_t)item_inputs[b] * DD + tu];
    float prod = hy * ti;
    #pragma unroll
    for (int off = 32; off > 0; off >>= 1)
      prod += __shfl_down(prod, off, 64);
    if (tu == 0) out[b] = prod;
  }
}

extern "C" void kernel_launch(void* const* d_in, const int* in_sizes, int n_in,
                              void* d_out, int out_size, void* d_ws, size_t ws_size,
                              hipStream_t stream) {
  const int*   user_inputs   = (const int*)d_in[0];
  const int*   record_inputs = (const int*)d_in[1];
  const int*   item_inputs   = (const int*)d_in[2];
  const int*   item_cat      = (const int*)d_in[3];
  const float* user_emb      = (const float*)d_in[4];
  const float* item_emb      = (const float*)d_in[5];
  const float* W1            = (const float*)d_in[6];
  const float* b1            = (const float*)d_in[7];
  const float* W2            = (const float*)d_in[8];
  const float* b2            = (const float*)d_in[9];
  const float* Wt1           = (const float*)d_in[10];
  const float* bt1           = (const float*)d_in[11];
  const float* Wt2           = (const float*)d_in[12];
  const float* bt2           = (const float*)d_in[13];
  float* out = (float*)d_out;

  din_fused<<<NB / UPB, 512, 0, stream>>>(user_inputs, record_inputs, item_inputs,
                                          item_cat, user_emb, item_emb,
                                          W1, b1, W2, b2, Wt1, bt1, Wt2, bt2, out);
}